// Round 2
// baseline (1047.787 us; speedup 1.0000x reference)
//
#include <hip/hip_runtime.h>
#include <math.h>

#define N_NODES 100000
#define N_EDGES 3200000
#define IN_DIM  128
#define OUT_DIM 64

// ---------------------------------------------------------------------------
// Kernel 1: base = feature @ W_lin ; u1 = tanh(base)
// ---------------------------------------------------------------------------
__global__ __launch_bounds__(256) void gemm_base_tanh(
    const float* __restrict__ feature,
    const float* __restrict__ Wlin,
    float* __restrict__ base,
    float* __restrict__ u1)
{
    int row = blockIdx.x * 256 + threadIdx.x;
    if (row >= N_NODES) return;

    const float4* frow = reinterpret_cast<const float4*>(feature + (size_t)row * IN_DIM);
    const float4* Wv   = reinterpret_cast<const float4*>(Wlin);   // [IN_DIM][16] float4

    float4 acc[16];
#pragma unroll
    for (int j = 0; j < 16; ++j) acc[j] = make_float4(0.f, 0.f, 0.f, 0.f);

    for (int k4 = 0; k4 < IN_DIM / 4; ++k4) {
        float4 f = frow[k4];
#pragma unroll
        for (int kk = 0; kk < 4; ++kk) {
            float fk = (kk == 0) ? f.x : (kk == 1) ? f.y : (kk == 2) ? f.z : f.w;
            const float4* wr = Wv + (size_t)(k4 * 4 + kk) * (OUT_DIM / 4);
#pragma unroll
            for (int j = 0; j < 16; ++j) {
                float4 w = wr[j];
                acc[j].x = fmaf(fk, w.x, acc[j].x);
                acc[j].y = fmaf(fk, w.y, acc[j].y);
                acc[j].z = fmaf(fk, w.z, acc[j].z);
                acc[j].w = fmaf(fk, w.w, acc[j].w);
            }
        }
    }

    float4* brow = reinterpret_cast<float4*>(base + (size_t)row * OUT_DIM);
    float4* urow = reinterpret_cast<float4*>(u1   + (size_t)row * OUT_DIM);
#pragma unroll
    for (int j = 0; j < 16; ++j) {
        brow[j] = acc[j];
        float4 t;
        t.x = tanhf(acc[j].x);
        t.y = tanhf(acc[j].y);
        t.z = tanhf(acc[j].z);
        t.w = tanhf(acc[j].w);
        urow[j] = t;
    }
}

// ---------------------------------------------------------------------------
// CSR build phase (counting sort by dst) — int atomics only, L2-resident.
// ---------------------------------------------------------------------------
__global__ __launch_bounds__(256) void hist_deg(
    const int* __restrict__ dst, int* __restrict__ deg)
{
    int i = blockIdx.x * 256 + threadIdx.x;
    int stride = gridDim.x * 256;
    for (; i < N_EDGES; i += stride)
        atomicAdd(&deg[dst[i]], 1);
}

__global__ __launch_bounds__(1024) void scan_offsets(
    const int* __restrict__ deg,
    int* __restrict__ offsets,
    int* __restrict__ cursor)
{
    __shared__ int sums[1024];
    int t = threadIdx.x;
    const int C = (N_NODES + 1023) / 1024;   // 98 per thread
    int beg = t * C;
    int end = beg + C; if (end > N_NODES) end = N_NODES;

    int s = 0;
    for (int i = beg; i < end; ++i) s += deg[i];
    sums[t] = s;
    __syncthreads();

    // Hillis-Steele inclusive scan over 1024 thread-sums
    for (int off = 1; off < 1024; off <<= 1) {
        int v = (t >= off) ? sums[t - off] : 0;
        __syncthreads();
        sums[t] += v;
        __syncthreads();
    }

    int excl = (t == 0) ? 0 : sums[t - 1];
    for (int i = beg; i < end; ++i) {
        offsets[i] = excl;
        cursor[i]  = excl;
        excl += deg[i];
    }
    if (t == 1023) offsets[N_NODES] = sums[1023];
}

__global__ __launch_bounds__(256) void fill_csr(
    const int* __restrict__ src,
    const int* __restrict__ dst,
    int* __restrict__ cursor,
    int* __restrict__ csr_src)
{
    int i = blockIdx.x * 256 + threadIdx.x;
    int stride = gridDim.x * 256;
    for (; i < N_EDGES; i += stride) {
        int p = atomicAdd(&cursor[dst[i]], 1);
        csr_src[p] = src[i];
    }
}

// ---------------------------------------------------------------------------
// Kernel 2': m[n] = sum_{e in CSR[n]} u1[csr_src[e]]  — wave per node,
// lane = column. No float atomics; u1 rows are cache-resident 256B gathers.
// ---------------------------------------------------------------------------
__global__ __launch_bounds__(256) void gather_sum(
    const int* __restrict__ offsets,
    const int* __restrict__ csr_src,
    const float* __restrict__ u1,
    float* __restrict__ m)
{
    int lane = threadIdx.x & 63;
    int node = (blockIdx.x * 256 + threadIdx.x) >> 6;
    if (node >= N_NODES) return;

    int beg = offsets[node];
    int end = offsets[node + 1];

    float acc = 0.f;
    int e = beg;
    // 4-deep unroll: 4 independent gathers in flight
    for (; e + 4 <= end; e += 4) {
        int s0 = csr_src[e];
        int s1 = csr_src[e + 1];
        int s2 = csr_src[e + 2];
        int s3 = csr_src[e + 3];
        float v0 = u1[(size_t)s0 * OUT_DIM + lane];
        float v1 = u1[(size_t)s1 * OUT_DIM + lane];
        float v2 = u1[(size_t)s2 * OUT_DIM + lane];
        float v3 = u1[(size_t)s3 * OUT_DIM + lane];
        acc += (v0 + v1) + (v2 + v3);
    }
    for (; e < end; ++e)
        acc += u1[(size_t)csr_src[e] * OUT_DIM + lane];

    m[(size_t)node * OUT_DIM + lane] = acc;
}

// ---------------------------------------------------------------------------
// Kernel 3: out = tanh(base + relu(m @ W_d1) @ W_d2)
// ---------------------------------------------------------------------------
__global__ __launch_bounds__(256) void dense_tanh(
    const float* __restrict__ m,
    const float* __restrict__ W1,
    const float* __restrict__ W2,
    const float* __restrict__ base,
    float* __restrict__ out)
{
    int row = blockIdx.x * 256 + threadIdx.x;
    if (row >= N_NODES) return;

    const float4* mrow = reinterpret_cast<const float4*>(m + (size_t)row * OUT_DIM);
    const float4* W1v  = reinterpret_cast<const float4*>(W1);  // [64][16] float4
    const float4* W2v  = reinterpret_cast<const float4*>(W2);

    // ---- layer 1: t = relu(m @ W1) ----
    float4 t[16];
#pragma unroll
    for (int j = 0; j < 16; ++j) t[j] = make_float4(0.f, 0.f, 0.f, 0.f);

    for (int k4 = 0; k4 < OUT_DIM / 4; ++k4) {
        float4 mv = mrow[k4];
#pragma unroll
        for (int kk = 0; kk < 4; ++kk) {
            float mk = (kk == 0) ? mv.x : (kk == 1) ? mv.y : (kk == 2) ? mv.z : mv.w;
            const float4* wr = W1v + (size_t)(k4 * 4 + kk) * 16;
#pragma unroll
            for (int j = 0; j < 16; ++j) {
                float4 w = wr[j];
                t[j].x = fmaf(mk, w.x, t[j].x);
                t[j].y = fmaf(mk, w.y, t[j].y);
                t[j].z = fmaf(mk, w.z, t[j].z);
                t[j].w = fmaf(mk, w.w, t[j].w);
            }
        }
    }
#pragma unroll
    for (int j = 0; j < 16; ++j) {
        t[j].x = fmaxf(t[j].x, 0.f);
        t[j].y = fmaxf(t[j].y, 0.f);
        t[j].z = fmaxf(t[j].z, 0.f);
        t[j].w = fmaxf(t[j].w, 0.f);
    }

    // ---- layer 2: h = t @ W2 ----
    float4 h[16];
#pragma unroll
    for (int j = 0; j < 16; ++j) h[j] = make_float4(0.f, 0.f, 0.f, 0.f);

#pragma unroll
    for (int k = 0; k < OUT_DIM; ++k) {
        float4 tv = t[k / 4];
        float tk = ((k & 3) == 0) ? tv.x : ((k & 3) == 1) ? tv.y : ((k & 3) == 2) ? tv.z : tv.w;
        const float4* wr = W2v + (size_t)k * 16;
#pragma unroll
        for (int j = 0; j < 16; ++j) {
            float4 w = wr[j];
            h[j].x = fmaf(tk, w.x, h[j].x);
            h[j].y = fmaf(tk, w.y, h[j].y);
            h[j].z = fmaf(tk, w.z, h[j].z);
            h[j].w = fmaf(tk, w.w, h[j].w);
        }
    }

    const float4* brow = reinterpret_cast<const float4*>(base + (size_t)row * OUT_DIM);
    float4* orow = reinterpret_cast<float4*>(out + (size_t)row * OUT_DIM);
#pragma unroll
    for (int j = 0; j < 16; ++j) {
        float4 b = brow[j];
        float4 o;
        o.x = tanhf(b.x + h[j].x);
        o.y = tanhf(b.y + h[j].y);
        o.z = tanhf(b.z + h[j].z);
        o.w = tanhf(b.w + h[j].w);
        orow[j] = o;
    }
}

// ---------------------------------------------------------------------------
extern "C" void kernel_launch(void* const* d_in, const int* in_sizes, int n_in,
                              void* d_out, int out_size, void* d_ws, size_t ws_size,
                              hipStream_t stream)
{
    const float* feature = (const float*)d_in[0];
    const int*   src     = (const int*)d_in[1];
    const int*   dst     = (const int*)d_in[2];
    const float* W_lin   = (const float*)d_in[3];
    const float* W_d1    = (const float*)d_in[4];
    const float* W_d2    = (const float*)d_in[5];
    float* out = (float*)d_out;

    const size_t NODE_F = (size_t)N_NODES * OUT_DIM;   // 6.4M floats, 25.6 MB

    // Workspace layout (16B-aligned chunks): ~90.4 MB total
    float* base    = (float*)d_ws;                 // 25.6 MB
    float* u1      = base + NODE_F;                // 25.6 MB
    float* m       = u1 + NODE_F;                  // 25.6 MB
    int*   deg     = (int*)(m + NODE_F);           // 400 KB (doubles as scratch)
    int*   offsets = deg + N_NODES;                // 400 KB + 4
    int*   cursor  = offsets + (N_NODES + 1);      // 400 KB
    int*   csr_src = cursor + N_NODES;             // 12.8 MB

    // iter 1 collapses: u0 == 0 -> m == 0 -> h == 0 -> u1 = tanh(feature@W_lin)
    hipMemsetAsync(deg, 0, N_NODES * sizeof(int), stream);

    int row_blocks = (N_NODES + 255) / 256;
    gemm_base_tanh<<<row_blocks, 256, 0, stream>>>(feature, W_lin, base, u1);

    hist_deg<<<2048, 256, 0, stream>>>(dst, deg);
    scan_offsets<<<1, 1024, 0, stream>>>(deg, offsets, cursor);
    fill_csr<<<2048, 256, 0, stream>>>(src, dst, cursor, csr_src);

    int node_wave_blocks = (N_NODES * 64 + 255) / 256;
    gather_sum<<<node_wave_blocks, 256, 0, stream>>>(offsets, csr_src, u1, m);

    dense_tanh<<<row_blocks, 256, 0, stream>>>(m, W_d1, W_d2, base, out);
}